// Round 2
// baseline (619.941 us; speedup 1.0000x reference)
//
#include <hip/hip_runtime.h>
#include <stdint.h>
#include <math.h>

typedef __attribute__((ext_vector_type(8))) __bf16 bf16x8;
typedef __attribute__((ext_vector_type(4))) float f32x4;

#define GLD16(gp, lp)                                                     \
  __builtin_amdgcn_global_load_lds(                                       \
      (__attribute__((address_space(1))) void*)(gp),                      \
      (__attribute__((address_space(3))) void*)(lp), 16, 0, 0)

__device__ __forceinline__ unsigned short f2bf(float f) {
  union { float f; unsigned int u; } v; v.f = f;
  unsigned int u = v.u;
  u += 0x7fffu + ((u >> 16) & 1u);   // RTN-even (exact for our small ints)
  return (unsigned short)(u >> 16);
}

// ---------- prep W: qw = rint(clip(w*127)) in fp64, stored as exact bf16 int
__global__ void __launch_bounds__(256) k_prep_w(const float* __restrict__ wx,
                                                const float* __restrict__ wh,
                                                unsigned short* __restrict__ Wq) {
  int i = blockIdx.x * 256 + threadIdx.x;
  int e = i << 2;
  int g = e >> 12;          // row (4096 cols: [qwx | qwh])
  int c = e & 4095;
  const float* src = (c < 2048) ? (wx + g * 2048 + c) : (wh + g * 2048 + (c - 2048));
  float4 v = *(const float4*)src;
  ushort4 o;
  o.x = f2bf((float)rint(fmin(fmax((double)v.x * 127.0, -127.0), 127.0)));
  o.y = f2bf((float)rint(fmin(fmax((double)v.y * 127.0, -127.0), 127.0)));
  o.z = f2bf((float)rint(fmin(fmax((double)v.z * 127.0, -127.0), 127.0)));
  o.w = f2bf((float)rint(fmin(fmax((double)v.w * 127.0, -127.0), 127.0)));
  *(ushort4*)(Wq + e) = o;
}

// ---------- prep A: Aq[1024][10240] = [A4 | A3 | A2 | A1 | qx]
// hx = A1*2^-5 + A2*2^-14 + A3*2^-23 + A4*2^-32 (exact; digits |.|<=256)
__global__ void __launch_bounds__(256) k_prep_a(const float* __restrict__ x,
                                                const float* __restrict__ hx,
                                                unsigned short* __restrict__ Aq) {
  int i = blockIdx.x * 256 + threadIdx.x;   // 524288 threads
  int e = i << 2;
  int b = e >> 11;
  int c = e & 2047;
  float4 xv = *(const float4*)(x + b * 2048 + c);
  float4 hv = *(const float4*)(hx + b * 2048 + c);
  ushort4 q4, s1, s2, s3, s4;
  float xa[4] = {xv.x, xv.y, xv.z, xv.w};
  float ha[4] = {hv.x, hv.y, hv.z, hv.w};
  unsigned short* qp = (unsigned short*)&q4;
  unsigned short* p1 = (unsigned short*)&s1;
  unsigned short* p2 = (unsigned short*)&s2;
  unsigned short* p3 = (unsigned short*)&s3;
  unsigned short* p4 = (unsigned short*)&s4;
  #pragma unroll
  for (int j = 0; j < 4; ++j) {
    qp[j] = f2bf((float)rint(fmin(fmax((double)xa[j] * 127.0, -127.0), 127.0)));
    double r = (double)ha[j];
    double d1 = rint(r * 32.0);        r -= d1 * 0x1p-5;
    double d2 = rint(r * 0x1p14);      r -= d2 * 0x1p-14;
    double d3 = rint(r * 0x1p23);      r -= d3 * 0x1p-23;
    double d4 = rint(r * 0x1p32);
    p1[j] = f2bf((float)d1);
    p2[j] = f2bf((float)d2);
    p3[j] = f2bf((float)d3);
    p4[j] = f2bf((float)d4);
  }
  size_t base = (size_t)b * 10240;
  *(ushort4*)(Aq + base + 0 * 2048 + c) = s4;   // phase 0: A4 (scale 2^-32)
  *(ushort4*)(Aq + base + 1 * 2048 + c) = s3;   // phase 1: A3
  *(ushort4*)(Aq + base + 2 * 2048 + c) = s2;   // phase 2: A2
  *(ushort4*)(Aq + base + 3 * 2048 + c) = s1;   // phase 3: A1 (scale 2^-5)
  *(ushort4*)(Aq + base + 4 * 2048 + c) = q4;   // phase 4: qx
}

// ---------- fused exact GEMM + LSTM epilogue ----------
// tile M=128 (by), N=64 = 4 gates x 16 j (bx: j0 = bx*16). 4 waves 2x2,
// wave tile 64m x 32n. K = 10240 in 5 phases of 2048; exact integer sums
// per phase, Horner double-float fold between phases, fp64 epilogue.
__global__ void __launch_bounds__(256) k_gemm_lstm(
    const unsigned short* __restrict__ Aq, const unsigned short* __restrict__ Wq,
    const float* __restrict__ bx, const float* __restrict__ bh,
    const float* __restrict__ cx, float* __restrict__ out) {
  __shared__ __align__(16) unsigned short As[128 * 32];
  __shared__ __align__(16) unsigned short Bs[64 * 32];
  __shared__ float Lgo[2][128][17];

  const int t  = threadIdx.x;
  const int wv = t >> 6;
  const int ln = t & 63;
  const int wm = wv & 1;      // m half (64 rows)
  const int wn = wv >> 1;     // n half (32 cols)
  const int lr = ln & 15;
  const int q  = ln >> 4;

  const int j0 = blockIdx.x * 16;
  const int m0 = blockIdx.y * 128;

  // A staging: 128 rows x 64B = 2 issues; B: 64 rows x 64B = 1 issue.
  // XOR chunk swizzle: position p holds logical chunk p ^ ((r>>2)&3).
  int sA_off[2], lbaseA[2], sB_off, lbaseB;
  #pragma unroll
  for (int is = 0; is < 2; ++is) {
    int s = is * 256 + t;
    int r = s >> 2;
    int c = s & 3;
    int cl = c ^ ((r >> 2) & 3);
    sA_off[is] = (m0 + r) * 10240 + cl * 8;
    lbaseA[is] = (is * 256 + wv * 64) * 8;
  }
  {
    int r = t >> 2;
    int c = t & 3;
    int cl = c ^ ((r >> 2) & 3);
    int wrow = (r >> 4) * 2048 + j0 + (r & 15);   // gate*2048 + j
    sB_off = wrow * 4096 + cl * 8;
    lbaseB = (wv * 64) * 8;
  }

  const int cc = q ^ (lr >> 2);
  int aoff[4], boff[2];
  #pragma unroll
  for (int mf = 0; mf < 4; ++mf) aoff[mf] = (wm * 64 + mf * 16 + lr) * 32 + cc * 8;
  #pragma unroll
  for (int nf = 0; nf < 2; ++nf) boff[nf] = (wn * 32 + nf * 16 + lr) * 32 + cc * 8;

  f32x4 acc[4][2], Hh[4][2], Hl[4][2];
  #pragma unroll
  for (int mf = 0; mf < 4; ++mf)
    #pragma unroll
    for (int nf = 0; nf < 2; ++nf)
      acc[mf][nf] = (f32x4){0.f, 0.f, 0.f, 0.f};

  #pragma unroll 1
  for (int phase = 0; phase < 5; ++phase) {
    const int kA = phase * 2048;
    const int kB = (phase < 4) ? 2048 : 0;
    #pragma unroll 1
    for (int it = 0; it < 64; ++it) {
      const int kk = it * 32;
      __syncthreads();
      GLD16(Aq + sA_off[0] + kA + kk, &As[lbaseA[0]]);
      GLD16(Aq + sA_off[1] + kA + kk, &As[lbaseA[1]]);
      GLD16(Wq + sB_off + kB + kk, &Bs[lbaseB]);
      asm volatile("s_waitcnt vmcnt(0)" ::: "memory");
      __syncthreads();
      bf16x8 af[4], bfr[2];
      #pragma unroll
      for (int mf = 0; mf < 4; ++mf) af[mf] = *(const bf16x8*)&As[aoff[mf]];
      #pragma unroll
      for (int nf = 0; nf < 2; ++nf) bfr[nf] = *(const bf16x8*)&Bs[boff[nf]];
      #pragma unroll
      for (int mf = 0; mf < 4; ++mf)
        #pragma unroll
        for (int nf = 0; nf < 2; ++nf)
          acc[mf][nf] = __builtin_amdgcn_mfma_f32_16x16x32_bf16(
              af[mf], bfr[nf], acc[mf][nf], 0, 0, 0);
    }
    // phase boundary: fold exact integer sums (Horner, double-float)
    if (phase == 0) {
      #pragma unroll
      for (int mf = 0; mf < 4; ++mf)
        #pragma unroll
        for (int nf = 0; nf < 2; ++nf) {
          Hh[mf][nf] = acc[mf][nf];
          Hl[mf][nf] = (f32x4){0.f, 0.f, 0.f, 0.f};
          acc[mf][nf] = (f32x4){0.f, 0.f, 0.f, 0.f};
        }
    } else if (phase < 4) {
      #pragma unroll
      for (int mf = 0; mf < 4; ++mf)
        #pragma unroll
        for (int nf = 0; nf < 2; ++nf) {
          #pragma unroll
          for (int r = 0; r < 4; ++r) {
            float tv = Hh[mf][nf][r] * 0x1p-9f;       // exact
            float S  = acc[mf][nf][r];                // exact integer
            float s  = tv + S;
            float z  = s - tv;
            float e  = (tv - (s - z)) + (S - z);      // Knuth TwoSum error
            Hl[mf][nf][r] = Hl[mf][nf][r] * 0x1p-9f + e;
            Hh[mf][nf][r] = s;
          }
          acc[mf][nf] = (f32x4){0.f, 0.f, 0.f, 0.f};
        }
    }
  }
  // acc now holds exact Sx; Hh+Hl = S_A1 + S_A2*2^-9 + S_A3*2^-18 + S_A4*2^-27

  const double invsq = 1.0 / 16129.0;      // 1/127^2
  const double hsc   = 0x1p-5 / 127.0;     // h Horner scale

  __syncthreads();
  if (wn == 1) {   // gates g (nf=0) and o (nf=1): activate, stash q*127 ints
    #pragma unroll
    for (int mf = 0; mf < 4; ++mf) {
      #pragma unroll
      for (int nf = 0; nf < 2; ++nf) {
        int gate = 2 + nf;
        int gcol = gate * 2048 + j0 + lr;
        double bsum = (double)bx[gcol] + (double)bh[gcol];
        #pragma unroll
        for (int r = 0; r < 4; ++r) {
          double Sx = (double)acc[mf][nf][r];
          double Hd = ((double)Hh[mf][nf][r] + (double)Hl[mf][nf][r]) * hsc;
          double pre = Sx * invsq + Hd + bsum;
          double av = (gate == 2) ? tanh(pre) : (1.0 / (1.0 + exp(-pre)));
          double qv = rint(fmin(fmax(av * 127.0, -127.0), 127.0));
          int m = wm * 64 + mf * 16 + q * 4 + r;
          Lgo[nf][m][lr] = (float)qv;
        }
      }
    }
  }
  __syncthreads();
  if (wn == 0) {   // gates f (nf=0) and i (nf=1): combine + store
    #pragma unroll
    for (int mf = 0; mf < 4; ++mf) {
      int gcf = j0 + lr;
      int gci = 2048 + j0 + lr;
      double bf_ = (double)bx[gcf] + (double)bh[gcf];
      double bi_ = (double)bx[gci] + (double)bh[gci];
      #pragma unroll
      for (int r = 0; r < 4; ++r) {
        int m = wm * 64 + mf * 16 + q * 4 + r;
        double fpre = (double)acc[mf][0][r] * invsq +
                      ((double)Hh[mf][0][r] + (double)Hl[mf][0][r]) * hsc + bf_;
        double ipre = (double)acc[mf][1][r] * invsq +
                      ((double)Hh[mf][1][r] + (double)Hl[mf][1][r]) * hsc + bi_;
        double fs = 1.0 / (1.0 + exp(-fpre));
        double is = 1.0 / (1.0 + exp(-ipre));
        double fv = rint(fmin(fmax(fs * 127.0, -127.0), 127.0)) / 127.0;
        double iv = rint(fmin(fmax(is * 127.0, -127.0), 127.0)) / 127.0;
        double gv = (double)Lgo[0][m][lr] / 127.0;
        double ov = (double)Lgo[1][m][lr] / 127.0;
        int row = m0 + m;
        int col = j0 + lr;
        double cn = fv * (double)cx[row * 2048 + col] + iv * gv;
        double tq = rint(fmin(fmax(tanh(cn) * 127.0, -127.0), 127.0)) / 127.0;
        double hv = ov * tq;
        double cq = rint(fmin(fmax(cn * 127.0, -127.0), 127.0)) / 127.0;
        out[row * 2048 + col] = (float)hv;
        out[2097152 + row * 2048 + col] = (float)cq;
      }
    }
  }
}

// ---------- launch ----------
extern "C" void kernel_launch(void* const* d_in, const int* in_sizes, int n_in,
                              void* d_out, int out_size, void* d_ws, size_t ws_size,
                              hipStream_t stream) {
  const float* x  = (const float*)d_in[0];
  const float* hx = (const float*)d_in[1];
  const float* cx = (const float*)d_in[2];
  const float* wx = (const float*)d_in[3];
  const float* bx = (const float*)d_in[4];
  const float* wh = (const float*)d_in[5];
  const float* bh = (const float*)d_in[6];
  float* out = (float*)d_out;

  unsigned short* Wq = (unsigned short*)d_ws;                       // 67,108,864 B
  unsigned short* Aq = (unsigned short*)((char*)d_ws + 67108864);   // 20,971,520 B

  k_prep_w<<<dim3(32768), dim3(256), 0, stream>>>(wx, wh, Wq);
  k_prep_a<<<dim3(2048), dim3(256), 0, stream>>>(x, hx, Aq);
  k_gemm_lstm<<<dim3(128, 8), dim3(256), 0, stream>>>(Aq, Wq, bx, bh, cx, out);
}

// Round 3
// 387.549 us; speedup vs baseline: 1.5996x; 1.5996x over previous
//
#include <hip/hip_runtime.h>
#include <stdint.h>
#include <math.h>

typedef __attribute__((ext_vector_type(4))) int i32x4;
typedef __attribute__((ext_vector_type(4))) float f32x4;

#define GLD16(gp, lp)                                                     \
  __builtin_amdgcn_global_load_lds(                                       \
      (__attribute__((address_space(1))) void*)(gp),                      \
      (__attribute__((address_space(3))) void*)(lp), 16, 0, 0)

// ---------- prep W: qw = rint(clip(w*127)) -> int8, Wq[8192][4096] = [qwx|qwh]
__global__ void __launch_bounds__(256) k_prep_w(const float* __restrict__ wx,
                                                const float* __restrict__ wh,
                                                signed char* __restrict__ Wq) {
  int i = blockIdx.x * 256 + threadIdx.x;
  int e = i << 2;
  int g = e >> 12;
  int c = e & 4095;
  const float* src = (c < 2048) ? (wx + g * 2048 + c) : (wh + g * 2048 + (c - 2048));
  float4 v = *(const float4*)src;
  char4 o;
  o.x = (signed char)(int)rint(fmin(fmax((double)v.x * 127.0, -127.0), 127.0));
  o.y = (signed char)(int)rint(fmin(fmax((double)v.y * 127.0, -127.0), 127.0));
  o.z = (signed char)(int)rint(fmin(fmax((double)v.z * 127.0, -127.0), 127.0));
  o.w = (signed char)(int)rint(fmin(fmax((double)v.w * 127.0, -127.0), 127.0));
  *(char4*)(Wq + e) = o;
}

// ---------- prep A: Aq[1024][12288] = [d5|d4|d3|d2|d1|qx] int8 slices
// hx = d1*2^-4 + d2*2^-11 + d3*2^-18 + d4*2^-25 + d5*2^-32 (exact, |d|<=84)
__global__ void __launch_bounds__(256) k_prep_a(const float* __restrict__ x,
                                                const float* __restrict__ hx,
                                                signed char* __restrict__ Aq) {
  int i = blockIdx.x * 256 + threadIdx.x;   // 524288 threads
  int e = i << 2;
  int b = e >> 11;
  int c = e & 2047;
  float4 xv = *(const float4*)(x + b * 2048 + c);
  float4 hv = *(const float4*)(hx + b * 2048 + c);
  float xa[4] = {xv.x, xv.y, xv.z, xv.w};
  float ha[4] = {hv.x, hv.y, hv.z, hv.w};
  char4 q4, s1, s2, s3, s4, s5;
  signed char* qp = (signed char*)&q4;
  signed char* p1 = (signed char*)&s1;
  signed char* p2 = (signed char*)&s2;
  signed char* p3 = (signed char*)&s3;
  signed char* p4 = (signed char*)&s4;
  signed char* p5 = (signed char*)&s5;
  #pragma unroll
  for (int j = 0; j < 4; ++j) {
    qp[j] = (signed char)(int)rint(fmin(fmax((double)xa[j] * 127.0, -127.0), 127.0));
    double r = (double)ha[j];
    double d1 = rint(r * 16.0);     r -= d1 * 0x1p-4;
    double d2 = rint(r * 0x1p11);   r -= d2 * 0x1p-11;
    double d3 = rint(r * 0x1p18);   r -= d3 * 0x1p-18;
    double d4 = rint(r * 0x1p25);   r -= d4 * 0x1p-25;
    double d5 = rint(r * 0x1p32);
    p1[j] = (signed char)(int)d1;
    p2[j] = (signed char)(int)d2;
    p3[j] = (signed char)(int)d3;
    p4[j] = (signed char)(int)d4;
    p5[j] = (signed char)(int)d5;
  }
  size_t base = (size_t)b * 12288;
  *(char4*)(Aq + base + 0 * 2048 + c) = s5;   // phase 0 (smallest first)
  *(char4*)(Aq + base + 1 * 2048 + c) = s4;
  *(char4*)(Aq + base + 2 * 2048 + c) = s3;
  *(char4*)(Aq + base + 3 * 2048 + c) = s2;
  *(char4*)(Aq + base + 4 * 2048 + c) = s1;
  *(char4*)(Aq + base + 5 * 2048 + c) = q4;   // phase 5: qx
}

// ---------- fused exact i8 GEMM + LSTM epilogue ----------
// tile M=128, N=64 (4 gates x 16 j). 4 waves 2x2, wave tile 64x32.
// BK=128 i8; 6 phases x 16 iters; i32 exact accumulate; TwoSum Horner fold
// between digit phases; fp64 epilogue. LDS rows are 128 B (= bank span),
// chunk position p holds logical chunk p ^ (row&7) -> 2-way (free) b128 reads.
__global__ void __launch_bounds__(256, 3) k_gemm_lstm(
    const signed char* __restrict__ Aq, const signed char* __restrict__ Wq,
    const float* __restrict__ bx, const float* __restrict__ bh,
    const float* __restrict__ cx, float* __restrict__ out) {
  __shared__ __align__(16) signed char smem[24576];
  signed char* As = smem;            // [128][128] i8
  signed char* Bs = smem + 16384;    // [64][128] i8

  const int t  = threadIdx.x;
  const int wv = t >> 6;
  const int ln = t & 63;
  const int wm = wv & 1;
  const int wn = wv >> 1;
  const int lr = ln & 15;
  const int q  = ln >> 4;

  const int j0 = blockIdx.x * 16;
  const int m0 = blockIdx.y * 128;

  // staging source offsets (XOR-swizzled chunks)
  int sA[4];
  #pragma unroll
  for (int is = 0; is < 4; ++is) {
    int s = is * 256 + t;
    int r = s >> 3;
    int c = s & 7;
    int cp = c ^ (r & 7);
    sA[is] = (m0 + r) * 12288 + cp * 16;
  }
  int sB[2];
  #pragma unroll
  for (int is = 0; is < 2; ++is) {
    int s = is * 256 + t;
    int r = s >> 3;
    int c = s & 7;
    int cp = c ^ (r & 7);
    int wrow = (r >> 4) * 2048 + j0 + (r & 15);   // gate*2048 + j
    sB[is] = wrow * 4096 + cp * 16;
  }

  // LDS read offsets (s=0 half; s=1 half = offset ^ 64)
  int aoff[4], boff[2];
  const int swz = lr & 7;
  #pragma unroll
  for (int mf = 0; mf < 4; ++mf)
    aoff[mf] = (wm * 64 + mf * 16 + lr) * 128 + ((q ^ swz) * 16);
  #pragma unroll
  for (int nf = 0; nf < 2; ++nf)
    boff[nf] = (wn * 32 + nf * 16 + lr) * 128 + ((q ^ swz) * 16);

  i32x4 acc[4][2];
  f32x4 Hh[4][2], Hl[4][2];
  #pragma unroll
  for (int mf = 0; mf < 4; ++mf)
    #pragma unroll
    for (int nf = 0; nf < 2; ++nf)
      acc[mf][nf] = (i32x4){0, 0, 0, 0};

  #pragma unroll 1
  for (int ph = 0; ph < 6; ++ph) {
    const int kA = ph * 2048;
    const int kB = (ph < 5) ? 2048 : 0;
    #pragma unroll 1
    for (int it = 0; it < 16; ++it) {
      const int kk = it * 128;
      __syncthreads();
      #pragma unroll
      for (int is = 0; is < 4; ++is)
        GLD16(Aq + sA[is] + kA + kk, As + is * 4096 + wv * 1024);
      #pragma unroll
      for (int is = 0; is < 2; ++is)
        GLD16(Wq + sB[is] + kB + kk, Bs + is * 4096 + wv * 1024);
      asm volatile("s_waitcnt vmcnt(0)" ::: "memory");
      __syncthreads();
      #pragma unroll
      for (int s = 0; s < 2; ++s) {
        const int sx = s << 6;
        i32x4 af[4], bf[2];
        #pragma unroll
        for (int mf = 0; mf < 4; ++mf) af[mf] = *(const i32x4*)&As[aoff[mf] ^ sx];
        #pragma unroll
        for (int nf = 0; nf < 2; ++nf) bf[nf] = *(const i32x4*)&Bs[boff[nf] ^ sx];
        #pragma unroll
        for (int mf = 0; mf < 4; ++mf)
          #pragma unroll
          for (int nf = 0; nf < 2; ++nf)
            acc[mf][nf] = __builtin_amdgcn_mfma_i32_16x16x64_i8(
                af[mf], bf[nf], acc[mf][nf], 0, 0, 0);
      }
    }
    // phase-boundary Horner fold (exact ints; TwoSum keeps it exact)
    if (ph == 0) {
      #pragma unroll
      for (int mf = 0; mf < 4; ++mf)
        #pragma unroll
        for (int nf = 0; nf < 2; ++nf) {
          #pragma unroll
          for (int r = 0; r < 4; ++r) {
            Hh[mf][nf][r] = (float)acc[mf][nf][r];
            Hl[mf][nf][r] = 0.f;
          }
          acc[mf][nf] = (i32x4){0, 0, 0, 0};
        }
    } else if (ph < 5) {
      #pragma unroll
      for (int mf = 0; mf < 4; ++mf)
        #pragma unroll
        for (int nf = 0; nf < 2; ++nf) {
          #pragma unroll
          for (int r = 0; r < 4; ++r) {
            float tv = Hh[mf][nf][r] * 0x1p-7f;   // exact (pow2)
            float S  = (float)acc[mf][nf][r];     // exact (|S| < 2^20)
            float sm = tv + S;
            float z  = sm - tv;
            float e  = (tv - (sm - z)) + (S - z);
            Hl[mf][nf][r] = Hl[mf][nf][r] * 0x1p-7f + e;
            Hh[mf][nf][r] = sm;
          }
          acc[mf][nf] = (i32x4){0, 0, 0, 0};
        }
    }
  }
  // acc = exact Sx (i32); Hh+Hl = S_d1 + S_d2*2^-7 + ... + S_d5*2^-28

  const double invsq = 1.0 / 16129.0;     // 1/127^2
  const double hsc   = 0x1p-4 / 127.0;    // digit-chain scale

  float (*Lgo)[128][17] = (float(*)[128][17])smem;   // overlay on As/Bs

  __syncthreads();
  if (wn == 1) {   // gates g (nf=0), o (nf=1): activate, stash q*127 ints
    #pragma unroll
    for (int mf = 0; mf < 4; ++mf) {
      #pragma unroll
      for (int nf = 0; nf < 2; ++nf) {
        int gate = 2 + nf;
        int gcol = gate * 2048 + j0 + lr;
        double bsum = (double)bx[gcol] + (double)bh[gcol];
        #pragma unroll
        for (int r = 0; r < 4; ++r) {
          double Sx = (double)acc[mf][nf][r];
          double Hd = ((double)Hh[mf][nf][r] + (double)Hl[mf][nf][r]) * hsc;
          double pre = Sx * invsq + Hd + bsum;
          double av = (gate == 2) ? tanh(pre) : (1.0 / (1.0 + exp(-pre)));
          double qv = rint(fmin(fmax(av * 127.0, -127.0), 127.0));
          int m = wm * 64 + mf * 16 + q * 4 + r;
          Lgo[nf][m][lr] = (float)qv;
        }
      }
    }
  }
  __syncthreads();
  if (wn == 0) {   // gates f (nf=0), i (nf=1): combine + store
    #pragma unroll
    for (int mf = 0; mf < 4; ++mf) {
      int gcf = j0 + lr;
      int gci = 2048 + j0 + lr;
      double bf_ = (double)bx[gcf] + (double)bh[gcf];
      double bi_ = (double)bx[gci] + (double)bh[gci];
      #pragma unroll
      for (int r = 0; r < 4; ++r) {
        int m = wm * 64 + mf * 16 + q * 4 + r;
        double fpre = (double)acc[mf][0][r] * invsq +
                      ((double)Hh[mf][0][r] + (double)Hl[mf][0][r]) * hsc + bf_;
        double ipre = (double)acc[mf][1][r] * invsq +
                      ((double)Hh[mf][1][r] + (double)Hl[mf][1][r]) * hsc + bi_;
        double fs = 1.0 / (1.0 + exp(-fpre));
        double is = 1.0 / (1.0 + exp(-ipre));
        double fv = rint(fmin(fmax(fs * 127.0, -127.0), 127.0)) / 127.0;
        double iv = rint(fmin(fmax(is * 127.0, -127.0), 127.0)) / 127.0;
        double gv = (double)Lgo[0][m][lr] / 127.0;
        double ov = (double)Lgo[1][m][lr] / 127.0;
        int row = m0 + m;
        int col = j0 + lr;
        double cn = fv * (double)cx[row * 2048 + col] + iv * gv;
        double tq = rint(fmin(fmax(tanh(cn) * 127.0, -127.0), 127.0)) / 127.0;
        double hv = ov * tq;
        double cq = rint(fmin(fmax(cn * 127.0, -127.0), 127.0)) / 127.0;
        out[row * 2048 + col] = (float)hv;
        out[2097152 + row * 2048 + col] = (float)cq;
      }
    }
  }
}

// ---------- launch ----------
extern "C" void kernel_launch(void* const* d_in, const int* in_sizes, int n_in,
                              void* d_out, int out_size, void* d_ws, size_t ws_size,
                              hipStream_t stream) {
  const float* x  = (const float*)d_in[0];
  const float* hx = (const float*)d_in[1];
  const float* cx = (const float*)d_in[2];
  const float* wx = (const float*)d_in[3];
  const float* bx = (const float*)d_in[4];
  const float* wh = (const float*)d_in[5];
  const float* bh = (const float*)d_in[6];
  float* out = (float*)d_out;

  signed char* Wq = (signed char*)d_ws;                       // 33,554,432 B
  signed char* Aq = (signed char*)d_ws + 33554432;            // 12,582,912 B

  k_prep_w<<<dim3(32768), dim3(256), 0, stream>>>(wx, wh, Wq);
  k_prep_a<<<dim3(2048), dim3(256), 0, stream>>>(x, hx, Aq);
  k_gemm_lstm<<<dim3(128, 8), dim3(256), 0, stream>>>(Aq, Wq, bx, bh, cx, out);
}